// Round 2
// baseline (31474.533 us; speedup 1.0000x reference)
//
#include <hip/hip_runtime.h>
#include <hip/hip_bf16.h>
#include <math.h>

#define Bz 64
#define Tz 256
#define Dz 512
#define Hz 1024
#define G3 3072
#define NB 256      // blocks in persistent recurrence kernel

#define KCHUNK 128
#define LDA 132     // padded LDS row stride (words) for A tiles

__device__ __forceinline__ float sigm(float x){ return 1.0f/(1.0f+expf(-x)); }

// ---------------- device-scope grid barrier (sense via generation counter) ----------------
__device__ __forceinline__ void gridbar(int* cnt, int* gen) {
  __syncthreads();
  __builtin_amdgcn_fence(__ATOMIC_RELEASE, "agent");   // flush this XCD's writes
  if (threadIdx.x == 0) {
    int g = __hip_atomic_load(gen, __ATOMIC_RELAXED, __HIP_MEMORY_SCOPE_AGENT);
    int prev = __hip_atomic_fetch_add(cnt, 1, __ATOMIC_RELAXED, __HIP_MEMORY_SCOPE_AGENT);
    if (prev == NB - 1) {
      __hip_atomic_store(cnt, 0, __ATOMIC_RELAXED, __HIP_MEMORY_SCOPE_AGENT);
      __hip_atomic_fetch_add(gen, 1, __ATOMIC_RELEASE, __HIP_MEMORY_SCOPE_AGENT);
    } else {
      while (__hip_atomic_load(gen, __ATOMIC_RELAXED, __HIP_MEMORY_SCOPE_AGENT) == g)
        __builtin_amdgcn_s_sleep(4);
    }
  }
  __syncthreads();
  __builtin_amdgcn_fence(__ATOMIC_ACQUIRE, "agent");   // invalidate stale cached lines
}

// ---------------- generic skinny GEMM core (used by kP only) ----------------
template<int COLS, int KDIM>
__device__ __forceinline__ void gemm_core(const float* __restrict__ Abase, int rowStride,
                                          const float* __restrict__ W,
                                          int jc0, int b, int tid,
                                          float* __restrict__ acc, float* __restrict__ lds)
{
#pragma unroll
  for (int c=0;c<COLS;c++) acc[c]=0.0f;
  constexpr int C4 = KCHUNK/4;
  for (int kb=0; kb<KDIM; kb+=KCHUNK) {
    __syncthreads();
    for (int i = tid; i < Bz*C4; i += 256) {
      int r  = i / C4;
      int c4 = i % C4;
      float4 v = *(const float4*)(Abase + (size_t)r*rowStride + kb + c4*4);
      *(float4*)(lds + r*LDA + c4*4) = v;
    }
    __syncthreads();
    const float* arow  = lds + b*LDA;
    const float* wbase = W + (size_t)jc0*KDIM + kb;
    for (int k=0;k<KCHUNK;k+=4) {
      float4 a = *(const float4*)(arow + k);
#pragma unroll
      for (int c=0;c<COLS;c++) {
        float4 w = *(const float4*)(wbase + (size_t)c*KDIM + k);
        acc[c] = fmaf(a.x,w.x,fmaf(a.y,w.y,fmaf(a.z,w.z,fmaf(a.w,w.w,acc[c]))));
      }
    }
  }
}

// ---- kP: pT[j][b] = ctx[b]·Wp[j] + bp[j] + (j<2H ? bh[j] : bc[j-2H])  (bias-folded, transposed)
__global__ __launch_bounds__(256)
void kP(const float* __restrict__ ctx, const float* __restrict__ Wp,
        const float* __restrict__ bp, const float* __restrict__ bh, const float* __restrict__ bc,
        float* __restrict__ pT)
{
  __shared__ float lds[Bz*LDA];
  int tid=threadIdx.x; int b=tid&63;
  int wv=__builtin_amdgcn_readfirstlane(tid>>6);
  int jc0 = blockIdx.x*16 + wv*4;
  float acc[4];
  gemm_core<4, Hz>(ctx, Hz, Wp, jc0, b, tid, acc, lds);
#pragma unroll
  for(int c=0;c<4;c++){
    int j=jc0+c;
    float v = acc[c] + bp[j] + (j < 2*Hz ? bh[j] : bc[j-2*Hz]);
    pT[(size_t)j*64 + b] = v;
  }
}

// ---- kA: igT[t][j][b] = x[b,t]·Wi[j] + bi[j] + pT[j][b]   (bf16, transposed, p folded)
// block: 32 cols (Wi tile LDS-resident, reused across 8 timesteps), A chunks in LDS.
__global__ __launch_bounds__(256)
void kA(const float* __restrict__ x, const float* __restrict__ Wi, const float* __restrict__ bi,
        const float* __restrict__ pT, __hip_bfloat16* __restrict__ igT)
{
  __shared__ float wt[32*Dz];     // 64 KB
  __shared__ float at[Bz*LDA];    // ~33 KB (128-k chunk, padded)
  int tid = threadIdx.x;
  int b = tid & 63;
  int wv = __builtin_amdgcn_readfirstlane(tid >> 6);
  int j0 = blockIdx.x * 32;
  int t0 = blockIdx.y * 8;
  {
    const float4* src = (const float4*)(Wi + (size_t)j0*Dz);
    float4* dst = (float4*)wt;
    for (int i = tid; i < 32*Dz/4; i += 256) dst[i] = src[i];
  }
  for (int it = 0; it < 8; it++) {
    int t = t0 + it;
    float acc[8];
#pragma unroll
    for (int c=0;c<8;c++) acc[c]=0.f;
    for (int kb = 0; kb < Dz; kb += KCHUNK) {
      __syncthreads();
      for (int i = tid; i < Bz*32; i += 256) {     // 2048 float4s
        int r = i >> 5, c4 = i & 31;
        float4 v = *(const float4*)(x + ((size_t)r*Tz + t)*Dz + kb + c4*4);
        *(float4*)(at + r*LDA + c4*4) = v;
      }
      __syncthreads();
      const float* arow = at + b*LDA;
      const float* wb = wt + (size_t)(wv*8)*Dz + kb;
#pragma unroll 4
      for (int k=0;k<KCHUNK;k+=4) {
        float4 a = *(const float4*)(arow + k);
#pragma unroll
        for (int c=0;c<8;c++) {
          float4 w = *(const float4*)(wb + (size_t)c*Dz + k);
          acc[c] = fmaf(a.x,w.x,fmaf(a.y,w.y,fmaf(a.z,w.z,fmaf(a.w,w.w,acc[c]))));
        }
      }
    }
#pragma unroll
    for (int c=0;c<8;c++) {
      int j = j0 + wv*8 + c;
      float v = acc[c] + bi[j] + pT[(size_t)j*64 + b];
      igT[((size_t)t*G3 + j)*64 + b] = __float2bfloat16(v);
    }
  }
}

// ---- persistent recurrence kernel: all 256 steps, 2 grid barriers/step.
// Block n owns gate cols [8n,8n+8) in phase1 (Wh LDS) and cols [4n,4n+4) in phase2 (Wc LDS).
// hT/rhT/iT are [k][b] f32 (coalesced wave reads).
__global__ __launch_bounds__(256)
void krec(const float* __restrict__ h0, const float* __restrict__ Wh, const float* __restrict__ Wc,
          const __hip_bfloat16* __restrict__ igT,
          float* __restrict__ hT, float* __restrict__ rhT, float* __restrict__ iT,
          float* __restrict__ out, int* bar)
{
  __shared__ float wh[8*Hz];   // 32 KB
  __shared__ float wc[4*Hz];   // 16 KB
  __shared__ float ot[4*64];   // out-transpose staging
  int tid = threadIdx.x;
  int b = tid & 63;
  int w = __builtin_amdgcn_readfirstlane(tid >> 6);
  int n = blockIdx.x;
  int* cnt = bar; int* gen = bar + 16;
  {
    const float4* s1 = (const float4*)(Wh + (size_t)n*8*Hz);
    float4* d1 = (float4*)wh;
    for (int i=tid;i<8*Hz/4;i+=256) d1[i] = s1[i];
    const float4* s2 = (const float4*)(Wc + (size_t)n*4*Hz);
    float4* d2 = (float4*)wc;
    for (int i=tid;i<4*Hz/4;i+=256) d2[i] = s2[i];
    int k = n*4 + w;                      // init hT (transpose h0)
    hT[(size_t)k*64 + b] = h0[(size_t)b*Hz + k];
  }
  gridbar(cnt, gen);
  for (int t=0;t<Tz;t++) {
    const __hip_bfloat16* igt = igT + (size_t)t*G3*64;
    { // phase1: r/i gates, 2 cols per wave
      int c0 = 2*w, c1 = c0+1;
      int j0 = n*8 + c0, j1 = j0 + 1;
      float e0=0.f,f0=0.f,e1=0.f,f1=0.f;
      const float* w0p = wh + (size_t)c0*Hz;
      const float* w1p = wh + (size_t)c1*Hz;
#pragma unroll 4
      for (int k=0;k<Hz;k+=4) {
        float a0 = hT[(size_t)(k+0)*64 + b];
        float a1 = hT[(size_t)(k+1)*64 + b];
        float a2 = hT[(size_t)(k+2)*64 + b];
        float a3 = hT[(size_t)(k+3)*64 + b];
        float4 u = *(const float4*)(w0p + k);
        float4 v = *(const float4*)(w1p + k);
        e0 = fmaf(a0,u.x,e0); f0 = fmaf(a1,u.y,f0);
        e0 = fmaf(a2,u.z,e0); f0 = fmaf(a3,u.w,f0);
        e1 = fmaf(a0,v.x,e1); f1 = fmaf(a1,v.y,f1);
        e1 = fmaf(a2,v.z,e1); f1 = fmaf(a3,v.w,f1);
      }
      float g0 = (float)igt[(size_t)j0*64 + b] + (e0 + f0);
      float g1 = (float)igt[(size_t)j1*64 + b] + (e1 + f1);
      g0 = sigm(g0); g1 = sigm(g1);
      if (n < 128) {  // r-gates: store r*h
        rhT[(size_t)j0*64+b] = g0 * hT[(size_t)j0*64+b];
        rhT[(size_t)j1*64+b] = g1 * hT[(size_t)j1*64+b];
      } else {        // i-gates
        iT[(size_t)(j0-Hz)*64+b] = g0;
        iT[(size_t)(j1-Hz)*64+b] = g1;
      }
    }
    gridbar(cnt, gen);
    { // phase2: n-gate + h update, 1 col per wave
      int jn = n*4 + w;
      const float* wp = wc + (size_t)w*Hz;
      float e0=0.f,f0=0.f,e2=0.f,f2=0.f;
#pragma unroll 4
      for (int k=0;k<Hz;k+=4) {
        float a0 = rhT[(size_t)(k+0)*64 + b];
        float a1 = rhT[(size_t)(k+1)*64 + b];
        float a2 = rhT[(size_t)(k+2)*64 + b];
        float a3 = rhT[(size_t)(k+3)*64 + b];
        float4 u = *(const float4*)(wp + k);
        e0 = fmaf(a0,u.x,e0); f0 = fmaf(a1,u.y,f0);
        e2 = fmaf(a2,u.z,e2); f2 = fmaf(a3,u.w,f2);
      }
      float g = (float)igt[(size_t)(2*Hz+jn)*64 + b] + ((e0+f0)+(e2+f2));
      float ng = tanhf(g);
      float hp = hT[(size_t)jn*64 + b];
      float iv = iT[(size_t)jn*64 + b];
      float hy = hp + iv*(ng - hp);
      hT[(size_t)jn*64 + b] = hy;
      ot[w*64 + b] = hy;
    }
    __syncthreads();
    if (tid < 64) {  // coalesce-ish out write: 16B per row
      float4 v = make_float4(ot[0*64+tid], ot[1*64+tid], ot[2*64+tid], ot[3*64+tid]);
      *(float4*)(out + ((size_t)tid*Tz + t)*Hz + n*4) = v;
    }
    gridbar(cnt, gen);
  }
}

// ---- final hidden state: hN[b][j] = hT[j][b]
__global__ __launch_bounds__(256)
void ktr(const float* __restrict__ hT, float* __restrict__ hN)
{
  __shared__ float tt[64*65];
  int tid = threadIdx.x;
  int j0 = blockIdx.x * 64;
  for (int q=0;q<16;q++) {
    int idx = tid + q*256;
    int jj = idx >> 6, bb = idx & 63;
    tt[jj*65 + bb] = hT[(size_t)(j0+jj)*64 + bb];
  }
  __syncthreads();
  for (int q=0;q<16;q++) {
    int idx = tid + q*256;
    int bb = idx >> 6, jj = idx & 63;
    hN[(size_t)bb*Hz + j0 + jj] = tt[jj*65 + bb];
  }
}

extern "C" void kernel_launch(void* const* d_in, const int* in_sizes, int n_in,
                              void* d_out, int out_size, void* d_ws, size_t ws_size,
                              hipStream_t stream)
{
  const float* x   = (const float*)d_in[0];
  const float* h0  = (const float*)d_in[1];
  const float* ctx = (const float*)d_in[2];
  const float* Wi  = (const float*)d_in[3];
  const float* bi  = (const float*)d_in[4];
  const float* Wh  = (const float*)d_in[5];
  const float* bh  = (const float*)d_in[6];
  const float* Wp  = (const float*)d_in[7];
  const float* bp  = (const float*)d_in[8];
  const float* Wc  = (const float*)d_in[9];
  const float* bc  = (const float*)d_in[10];
  float* out = (float*)d_out;

  char* wsp = (char*)d_ws;
  float* pT  = (float*)wsp; wsp += (size_t)G3*64*sizeof(float);      // 768 KB
  float* hT  = (float*)wsp; wsp += (size_t)Hz*64*sizeof(float);      // 256 KB
  float* rhT = (float*)wsp; wsp += (size_t)Hz*64*sizeof(float);      // 256 KB
  float* iT  = (float*)wsp; wsp += (size_t)Hz*64*sizeof(float);      // 256 KB
  int*   bar = (int*)wsp;   wsp += 256;                               // cnt/gen
  __hip_bfloat16* igT = (__hip_bfloat16*)wsp;                         // 96 MB

  hipMemsetAsync(bar, 0, 256, stream);
  kP  <<<dim3(G3/16),    256, 0, stream>>>(ctx, Wp, bp, bh, bc, pT);
  kA  <<<dim3(G3/32,32), 256, 0, stream>>>(x, Wi, bi, pT, igT);
  krec<<<dim3(NB),       256, 0, stream>>>(h0, Wh, Wc, igT, hT, rhT, iT, out, bar);
  ktr <<<dim3(Hz/64),    256, 0, stream>>>(hT, out + (size_t)Bz*Tz*Hz);
}

// Round 3
// 15319.406 us; speedup vs baseline: 2.0546x; 2.0546x over previous
//
#include <hip/hip_runtime.h>
#include <hip/hip_bf16.h>
#include <math.h>

#define Bz 64
#define Tz 256
#define Dz 512
#define Hz 1024
#define G3 3072
#define NBK 64      // blocks in persistent recurrence kernel

typedef short bf16x8 __attribute__((ext_vector_type(8)));
typedef float f32x4 __attribute__((ext_vector_type(4)));

__device__ __forceinline__ float sigm(float x){ return 1.0f/(1.0f+expf(-x)); }

__device__ __forceinline__ unsigned short f2b(float f){
  union{float f;unsigned u;}v; v.f=f;
  unsigned r = v.u + 0x7FFFu + ((v.u>>16)&1u);
  return (unsigned short)(r>>16);
}
__device__ __forceinline__ float b2f(unsigned short s){
  union{unsigned u;float f;}v; v.u = ((unsigned)s)<<16; return v.f;
}
__device__ __forceinline__ unsigned pk2(float a, float b){
  return (unsigned)f2b(a) | ((unsigned)f2b(b)<<16);
}

// ---------------- device-scope grid barrier ----------------
template<int NB>
__device__ __forceinline__ void gridbar(int* cnt, int* gen) {
  __syncthreads();
  __builtin_amdgcn_fence(__ATOMIC_RELEASE, "agent");
  if (threadIdx.x == 0) {
    int g = __hip_atomic_load(gen, __ATOMIC_RELAXED, __HIP_MEMORY_SCOPE_AGENT);
    int prev = __hip_atomic_fetch_add(cnt, 1, __ATOMIC_RELAXED, __HIP_MEMORY_SCOPE_AGENT);
    if (prev == NB - 1) {
      __hip_atomic_store(cnt, 0, __ATOMIC_RELAXED, __HIP_MEMORY_SCOPE_AGENT);
      __hip_atomic_fetch_add(gen, 1, __ATOMIC_RELEASE, __HIP_MEMORY_SCOPE_AGENT);
    } else {
      while (__hip_atomic_load(gen, __ATOMIC_RELAXED, __HIP_MEMORY_SCOPE_AGENT) == g)
        __builtin_amdgcn_s_sleep(2);
    }
  }
  __syncthreads();
  __builtin_amdgcn_fence(__ATOMIC_ACQUIRE, "agent");
}

// ---------------- f32 skinny GEMM core (kP only, tiny) ----------------
#define KCHUNK 128
#define LDA 132
template<int COLS, int KDIM>
__device__ __forceinline__ void gemm_core(const float* __restrict__ Abase, int rowStride,
                                          const float* __restrict__ W,
                                          int jc0, int b, int tid,
                                          float* __restrict__ acc, float* __restrict__ lds)
{
#pragma unroll
  for (int c=0;c<COLS;c++) acc[c]=0.0f;
  constexpr int C4 = KCHUNK/4;
  for (int kb=0; kb<KDIM; kb+=KCHUNK) {
    __syncthreads();
    for (int i = tid; i < Bz*C4; i += 256) {
      int r  = i / C4;
      int c4 = i % C4;
      float4 v = *(const float4*)(Abase + (size_t)r*rowStride + kb + c4*4);
      *(float4*)(lds + r*LDA + c4*4) = v;
    }
    __syncthreads();
    const float* arow  = lds + b*LDA;
    const float* wbase = W + (size_t)jc0*KDIM + kb;
    for (int k=0;k<KCHUNK;k+=4) {
      float4 a = *(const float4*)(arow + k);
#pragma unroll
      for (int c=0;c<COLS;c++) {
        float4 w = *(const float4*)(wbase + (size_t)c*KDIM + k);
        acc[c] = fmaf(a.x,w.x,fmaf(a.y,w.y,fmaf(a.z,w.z,fmaf(a.w,w.w,acc[c]))));
      }
    }
  }
}

// ---- kP: pT[j][b] = ctx[b]·Wp[j] + bp[j] + bi[j] + (j<2H ? bh[j] : bc[j-2H])
__global__ __launch_bounds__(256)
void kP(const float* __restrict__ ctx, const float* __restrict__ Wp,
        const float* __restrict__ bp, const float* __restrict__ bh,
        const float* __restrict__ bc, const float* __restrict__ bi,
        float* __restrict__ pT)
{
  __shared__ float lds[Bz*LDA];
  int tid=threadIdx.x; int b=tid&63;
  int wv=__builtin_amdgcn_readfirstlane(tid>>6);
  int jc0 = blockIdx.x*16 + wv*4;
  float acc[4];
  gemm_core<4, Hz>(ctx, Hz, Wp, jc0, b, tid, acc, lds);
#pragma unroll
  for(int c=0;c<4;c++){
    int j=jc0+c;
    float v = acc[c] + bp[j] + bi[j] + (j < 2*Hz ? bh[j] : bc[j-2*Hz]);
    pT[(size_t)j*64 + b] = v;
  }
}

// ---- kI: hF[j][b] = h0[b][j] (f32 transpose), hB[b][j] = bf16(h0)
__global__ __launch_bounds__(256)
void kI(const float* __restrict__ h0, float* __restrict__ hF, unsigned short* __restrict__ hB)
{
  __shared__ float tt[64*65];
  int tid = threadIdx.x;
  int j0 = blockIdx.x*64;
  for (int qq=0;qq<16;qq++) {
    int idx = tid + qq*256;
    int b = idx >> 6, j = idx & 63;
    tt[b*65 + j] = h0[(size_t)b*Hz + j0 + j];
  }
  __syncthreads();
  for (int qq=0;qq<16;qq++) {
    int idx = tid + qq*256;
    int j = idx >> 6, b = idx & 63;
    hF[(size_t)(j0+j)*64 + b] = tt[b*65 + j];
  }
  for (int g = blockIdx.x*256 + tid; g < Bz*Hz; g += 16*256) hB[g] = f2b(h0[g]);
}

// ---- kAm: MFMA input GEMM. igT[t][j][b] = bf16( x[b,t]·Wi[j] + pT[j][b] )
// grid (48 j-blocks of 64 cols, 16 t-blocks of 16 steps), 1024 threads (16 waves).
__global__ __launch_bounds__(1024)
void kAm(const float* __restrict__ x, const float* __restrict__ Wi,
         const float* __restrict__ pT, unsigned short* __restrict__ igT)
{
  __shared__ unsigned short wiF[4*16*64*8];  // 64 KB, fragment-swizzled Wi slice
  __shared__ unsigned short xs[64*528];      // 66 KB, x t-slice [b][k] bf16, padded rows
  __shared__ unsigned short igs[64*64];      // 8 KB, output staging [j][b]
  const int tid = threadIdx.x;
  const int lane = tid & 63;
  const int w = __builtin_amdgcn_readfirstlane(tid >> 6);
  const int j0 = blockIdx.x * 64;
  const int t0 = blockIdx.y * 16;
  const int mt = w >> 2, nt = w & 3;
  const int bb = nt*16 + (lane & 15);
  const int q  = lane >> 4;
  const int jl = mt*16 + q*4;

  for (int idx = tid; idx < 4096; idx += 1024) {
    int mt2 = idx >> 10;
    int ks = (idx >> 6) & 15;
    int ln = idx & 63;
    int j = j0 + mt2*16 + (ln & 15);
    int k = ks*32 + (ln >> 4)*8;
    const float* s = Wi + (size_t)j*Dz + k;
    unsigned short* d = wiF + (size_t)idx*8;
#pragma unroll
    for (int qq=0;qq<8;qq++) d[qq] = f2b(s[qq]);
  }
  float pv[4];
#pragma unroll
  for (int r=0;r<4;r++) pv[r] = pT[(size_t)(j0+jl+r)*64 + bb];

  for (int it=0; it<16; it++) {
    int t = t0 + it;
    __syncthreads();
    // stage x[b][t][:] -> xs bf16
    for (int i = tid; i < 64*32; i += 1024) {
      int b = i >> 5, c = i & 31;
      const float* s = x + ((size_t)b*Tz + t)*Dz + c*16;
      unsigned* d = (unsigned*)(xs + (size_t)b*528 + c*16);
      float4 v0 = *(const float4*)(s);
      float4 v1 = *(const float4*)(s+4);
      float4 v2 = *(const float4*)(s+8);
      float4 v3 = *(const float4*)(s+12);
      d[0]=pk2(v0.x,v0.y); d[1]=pk2(v0.z,v0.w);
      d[2]=pk2(v1.x,v1.y); d[3]=pk2(v1.z,v1.w);
      d[4]=pk2(v2.x,v2.y); d[5]=pk2(v2.z,v2.w);
      d[6]=pk2(v3.x,v3.y); d[7]=pk2(v3.z,v3.w);
    }
    __syncthreads();
    f32x4 acc = {0.f,0.f,0.f,0.f};
    const unsigned short* bsrc = xs + (size_t)bb*528 + q*8;
#pragma unroll
    for (int ks=0; ks<16; ks++) {
      bf16x8 a = *(const bf16x8*)(wiF + ((size_t)(mt*16+ks)*64 + lane)*8);
      bf16x8 b = *(const bf16x8*)(bsrc + ks*32);
      acc = __builtin_amdgcn_mfma_f32_16x16x32_bf16(a, b, acc, 0, 0, 0);
    }
#pragma unroll
    for (int r=0;r<4;r++) igs[(size_t)(jl+r)*64 + bb] = f2b(acc[r] + pv[r]);
    __syncthreads();
    if (tid < 512) {
      int j = tid >> 3, seg = tid & 7;
      *(uint4*)(igT + ((size_t)t*G3 + j0 + j)*64 + seg*8) =
        *(const uint4*)(igs + (size_t)j*64 + seg*8);
    }
  }
}

// ---- krec: persistent MFMA recurrence, 64 blocks x 1024 threads.
// Block n: phase1 owns gate cols [32n,32n+32) of 2048 (Wh bf16 frags in LDS);
//          phase2 owns cols [16n,16n+16) of 1024 (Wc frags in LDS).
// hF [j][b] f32 master; hB/rhB [b][k] bf16 MFMA B-operands; iT [j][b] f32.
__global__ __launch_bounds__(1024)
void krec(const float* __restrict__ Wh, const float* __restrict__ Wc,
          const unsigned short* __restrict__ igT,
          float* __restrict__ hF, unsigned short* __restrict__ hB,
          unsigned short* __restrict__ rhB, float* __restrict__ iT,
          float* __restrict__ out, int* bar)
{
  __shared__ unsigned short whF[2*32*64*8];  // 64 KB
  __shared__ unsigned short wcF[32*64*8];    // 32 KB
  __shared__ float red[16*64*4];             // 16 KB
  const int tid = threadIdx.x;
  const int lane = tid & 63;
  const int w = __builtin_amdgcn_readfirstlane(tid >> 6);
  const int n = blockIdx.x;
  int* cnt = bar; int* gen = bar + 16;

  // fragment-swizzle weight slices (f32 -> bf16), one-time
  for (int idx = tid; idx < 4096; idx += 1024) {
    int mt = idx >> 11;
    int ks = (idx >> 6) & 31;
    int ln = idx & 63;
    int j = n*32 + mt*16 + (ln & 15);
    int k = ks*32 + (ln >> 4)*8;
    const float* s = Wh + (size_t)j*Hz + k;
    unsigned short* d = whF + (size_t)idx*8;
#pragma unroll
    for (int qq=0;qq<8;qq++) d[qq] = f2b(s[qq]);
  }
  for (int idx = tid; idx < 2048; idx += 1024) {
    int ks = (idx >> 6) & 31;
    int ln = idx & 63;
    int j = n*16 + (ln & 15);
    int k = ks*32 + (ln >> 4)*8;
    const float* s = Wc + (size_t)j*Hz + k;
    unsigned short* d = wcF + (size_t)idx*8;
#pragma unroll
    for (int qq=0;qq<8;qq++) d[qq] = f2b(s[qq]);
  }
  gridbar<NBK>(cnt, gen);

  for (int t=0;t<Tz;t++) {
    const unsigned short* igt = igT + (size_t)t*G3*64;
    // ---------- phase 1: gates r,i ----------
    {
      int tp = w & 7, kh = w >> 3;        // split-K-2
      int mt = tp >> 2, nt = tp & 3;
      int bb = nt*16 + (lane & 15);
      int q  = lane >> 4;
      int jg = n*32 + mt*16 + q*4;        // global gate col in [0,2048)
      float igv[4], hv[4];
      if (w < 8) {
#pragma unroll
        for (int r=0;r<4;r++) igv[r] = b2f(igt[(size_t)(jg+r)*64 + bb]);
        if (n < 32) {
#pragma unroll
          for (int r=0;r<4;r++) hv[r] = hF[(size_t)(jg+r)*64 + bb];
        }
      }
      f32x4 acc = {0.f,0.f,0.f,0.f};
      const unsigned short* bsrc = hB + (size_t)bb*Hz + q*8;
      const unsigned short* asrc = whF + ((size_t)(mt*32 + kh*16)*64 + lane)*8;
#pragma unroll
      for (int ks=0; ks<16; ks++) {
        bf16x8 a = *(const bf16x8*)(asrc + (size_t)ks*64*8);
        bf16x8 b = *(const bf16x8*)(bsrc + (size_t)(kh*16+ks)*32);
        acc = __builtin_amdgcn_mfma_f32_16x16x32_bf16(a, b, acc, 0, 0, 0);
      }
      *(f32x4*)(red + ((size_t)w*64 + lane)*4) = acc;
      __syncthreads();
      if (w < 8) {
        f32x4 o  = *(const f32x4*)(red + ((size_t)w*64+lane)*4);
        f32x4 p2 = *(const f32x4*)(red + ((size_t)(w+8)*64+lane)*4);
        if (n < 32) {
          unsigned long long pk = 0;
#pragma unroll
          for (int r=0;r<4;r++) {
            float g = sigm(o[r] + p2[r] + igv[r]);
            pk |= (unsigned long long)f2b(g * hv[r]) << (16*r);
          }
          *(unsigned long long*)(rhB + (size_t)bb*Hz + jg) = pk;
        } else {
#pragma unroll
          for (int r=0;r<4;r++) {
            float g = sigm(o[r] + p2[r] + igv[r]);
            iT[(size_t)(jg-1024+r)*64 + bb] = g;
          }
        }
      }
    }
    gridbar<NBK>(cnt, gen);
    // ---------- phase 2: n-gate + h update ----------
    {
      int nt = w & 3, kq = w >> 2;        // split-K-4
      int bb = nt*16 + (lane & 15);
      int q  = lane >> 4;
      int jn = n*16 + q*4;                // global col in [0,1024)
      float igv[4], hv[4], iv[4];
      if (w < 4) {
#pragma unroll
        for (int r=0;r<4;r++) {
          igv[r] = b2f(igt[(size_t)(2048+jn+r)*64 + bb]);
          hv[r]  = hF[(size_t)(jn+r)*64 + bb];
          iv[r]  = iT[(size_t)(jn+r)*64 + bb];
        }
      }
      f32x4 acc = {0.f,0.f,0.f,0.f};
      const unsigned short* bsrc = rhB + (size_t)bb*Hz + q*8;
#pragma unroll
      for (int ks=0; ks<8; ks++) {
        bf16x8 a = *(const bf16x8*)(wcF + ((size_t)(kq*8+ks)*64 + lane)*8);
        bf16x8 b = *(const bf16x8*)(bsrc + (size_t)(kq*8+ks)*32);
        acc = __builtin_amdgcn_mfma_f32_16x16x32_bf16(a, b, acc, 0, 0, 0);
      }
      *(f32x4*)(red + ((size_t)w*64 + lane)*4) = acc;
      __syncthreads();
      if (w < 4) {
        f32x4 s0 = *(const f32x4*)(red + ((size_t)w*64+lane)*4);
        f32x4 s1 = *(const f32x4*)(red + ((size_t)(w+4)*64+lane)*4);
        f32x4 s2 = *(const f32x4*)(red + ((size_t)(w+8)*64+lane)*4);
        f32x4 s3 = *(const f32x4*)(red + ((size_t)(w+12)*64+lane)*4);
        float hy4[4];
        unsigned long long pk = 0;
#pragma unroll
        for (int r=0;r<4;r++) {
          float g  = s0[r]+s1[r]+s2[r]+s3[r] + igv[r];
          float ng = tanhf(g);
          float hy = hv[r] + iv[r]*(ng - hv[r]);
          hy4[r] = hy;
          hF[(size_t)(jn+r)*64 + bb] = hy;
          pk |= (unsigned long long)f2b(hy) << (16*r);
        }
        *(unsigned long long*)(hB + (size_t)bb*Hz + jn) = pk;
        float4 ov; ov.x=hy4[0]; ov.y=hy4[1]; ov.z=hy4[2]; ov.w=hy4[3];
        *(float4*)(out + ((size_t)bb*Tz + t)*Hz + jn) = ov;
      }
    }
    gridbar<NBK>(cnt, gen);
  }
}

// ---- final hidden state: out2[b][j] = hF[j][b]
__global__ __launch_bounds__(256)
void ktr(const float* __restrict__ hF, float* __restrict__ hN)
{
  __shared__ float tt[64*65];
  int tid = threadIdx.x;
  int j0 = blockIdx.x * 64;
  for (int qq=0;qq<16;qq++) {
    int idx = tid + qq*256;
    int jj = idx >> 6, bb = idx & 63;
    tt[jj*65 + bb] = hF[(size_t)(j0+jj)*64 + bb];
  }
  __syncthreads();
  for (int qq=0;qq<16;qq++) {
    int idx = tid + qq*256;
    int bb = idx >> 6, jj = idx & 63;
    hN[(size_t)bb*Hz + j0 + jj] = tt[jj*65 + bb];
  }
}

extern "C" void kernel_launch(void* const* d_in, const int* in_sizes, int n_in,
                              void* d_out, int out_size, void* d_ws, size_t ws_size,
                              hipStream_t stream)
{
  const float* x   = (const float*)d_in[0];
  const float* h0  = (const float*)d_in[1];
  const float* ctx = (const float*)d_in[2];
  const float* Wi  = (const float*)d_in[3];
  const float* bi  = (const float*)d_in[4];
  const float* Wh  = (const float*)d_in[5];
  const float* bh  = (const float*)d_in[6];
  const float* Wp  = (const float*)d_in[7];
  const float* bp  = (const float*)d_in[8];
  const float* Wc  = (const float*)d_in[9];
  const float* bc  = (const float*)d_in[10];
  float* out = (float*)d_out;

  char* wsp = (char*)d_ws;
  float* pT  = (float*)wsp; wsp += (size_t)G3*64*sizeof(float);       // 768 KB
  float* hF  = (float*)wsp; wsp += (size_t)Hz*64*sizeof(float);       // 256 KB
  float* iT  = (float*)wsp; wsp += (size_t)Hz*64*sizeof(float);       // 256 KB
  unsigned short* hB  = (unsigned short*)wsp; wsp += (size_t)Bz*Hz*2; // 128 KB
  unsigned short* rhB = (unsigned short*)wsp; wsp += (size_t)Bz*Hz*2; // 128 KB
  int* bar = (int*)wsp; wsp += 256;
  unsigned short* igT = (unsigned short*)wsp;                         // 96 MB

  hipMemsetAsync(bar, 0, 256, stream);
  kP  <<<dim3(G3/16),   256,  0, stream>>>(ctx, Wp, bp, bh, bc, bi, pT);
  kI  <<<dim3(16),      256,  0, stream>>>(h0, hF, hB);
  kAm <<<dim3(48,16),   1024, 0, stream>>>(x, Wi, pT, igT);
  krec<<<dim3(NBK),     1024, 0, stream>>>(Wh, Wc, igT, hF, hB, rhB, iT, out, bar);
  ktr <<<dim3(16),      256,  0, stream>>>(hF, out + (size_t)Bz*Tz*Hz);
}

// Round 4
// 6997.348 us; speedup vs baseline: 4.4981x; 2.1893x over previous
//
#include <hip/hip_runtime.h>
#include <hip/hip_bf16.h>
#include <math.h>

#define Bz 64
#define Tz 256
#define Dz 512
#define Hz 1024
#define G3 3072
#define NBK 64      // blocks in persistent recurrence kernel

typedef short bf16x8 __attribute__((ext_vector_type(8)));
typedef float f32x4 __attribute__((ext_vector_type(4)));

__device__ __forceinline__ float sigm(float x){ return 1.0f/(1.0f+expf(-x)); }

__device__ __forceinline__ unsigned short f2b(float f){
  union{float f;unsigned u;}v; v.f=f;
  unsigned r = v.u + 0x7FFFu + ((v.u>>16)&1u);
  return (unsigned short)(r>>16);
}
__device__ __forceinline__ float b2f(unsigned short s){
  union{unsigned u;float f;}v; v.u = ((unsigned)s)<<16; return v.f;
}
__device__ __forceinline__ unsigned pk2(float a, float b){
  return (unsigned)f2b(a) | ((unsigned)f2b(b)<<16);
}

// ---- coherent (agent-scope, sc1; no-fence) access helpers ----
__device__ __forceinline__ unsigned long long cld64(const void* p){
  return __hip_atomic_load((const unsigned long long*)p, __ATOMIC_RELAXED, __HIP_MEMORY_SCOPE_AGENT);
}
__device__ __forceinline__ void cst64(void* p, unsigned long long v){
  __hip_atomic_store((unsigned long long*)p, v, __ATOMIC_RELAXED, __HIP_MEMORY_SCOPE_AGENT);
}
__device__ __forceinline__ float2 cldf2(const float* p){
  union { unsigned long long u; float2 f; } U; U.u = cld64(p); return U.f;
}
__device__ __forceinline__ void cstf2(float* p, float a, float b){
  union { unsigned long long u; float2 f; } U; U.f = make_float2(a,b); cst64(p, U.u);
}
__device__ __forceinline__ bf16x8 cldb8(const unsigned short* p){
  union { unsigned long long u[2]; bf16x8 v; } U;
  U.u[0] = cld64(p); U.u[1] = cld64(p+4);
  return U.v;
}

// ---- fence-free grid barrier: arrival-flag array + leader publish ----
__device__ __forceinline__ void gbar(int* flags, int* gen, int ph) {
  __syncthreads();   // drains each wave's vmcnt -> all sc1 data stores agent-visible
  if (threadIdx.x == 0)
    __hip_atomic_store(flags + blockIdx.x, ph, __ATOMIC_RELAXED, __HIP_MEMORY_SCOPE_AGENT);
  if (blockIdx.x == 0 && threadIdx.x < 64) {
    while (!__all(__hip_atomic_load(flags + threadIdx.x, __ATOMIC_RELAXED,
                                    __HIP_MEMORY_SCOPE_AGENT) >= ph))
      __builtin_amdgcn_s_sleep(1);
    if (threadIdx.x == 0)
      __hip_atomic_store(gen, ph, __ATOMIC_RELAXED, __HIP_MEMORY_SCOPE_AGENT);
  }
  if (threadIdx.x == 0) {
    while (__hip_atomic_load(gen, __ATOMIC_RELAXED, __HIP_MEMORY_SCOPE_AGENT) < ph)
      __builtin_amdgcn_s_sleep(1);
  }
  __syncthreads();
}

// ---------------- f32 skinny GEMM core (kP only, tiny) ----------------
#define KCHUNK 128
#define LDA 132
template<int COLS, int KDIM>
__device__ __forceinline__ void gemm_core(const float* __restrict__ Abase, int rowStride,
                                          const float* __restrict__ W,
                                          int jc0, int b, int tid,
                                          float* __restrict__ acc, float* __restrict__ lds)
{
#pragma unroll
  for (int c=0;c<COLS;c++) acc[c]=0.0f;
  constexpr int C4 = KCHUNK/4;
  for (int kb=0; kb<KDIM; kb+=KCHUNK) {
    __syncthreads();
    for (int i = tid; i < Bz*C4; i += 256) {
      int r  = i / C4;
      int c4 = i % C4;
      float4 v = *(const float4*)(Abase + (size_t)r*rowStride + kb + c4*4);
      *(float4*)(lds + r*LDA + c4*4) = v;
    }
    __syncthreads();
    const float* arow  = lds + b*LDA;
    const float* wbase = W + (size_t)jc0*KDIM + kb;
    for (int k=0;k<KCHUNK;k+=4) {
      float4 a = *(const float4*)(arow + k);
#pragma unroll
      for (int c=0;c<COLS;c++) {
        float4 w = *(const float4*)(wbase + (size_t)c*KDIM + k);
        acc[c] = fmaf(a.x,w.x,fmaf(a.y,w.y,fmaf(a.z,w.z,fmaf(a.w,w.w,acc[c]))));
      }
    }
  }
}

// ---- kP: pT[j][b] = ctx[b]·Wp[j] + bp[j] + bi[j] + (j<2H ? bh[j] : bc[j-2H])
__global__ __launch_bounds__(256)
void kP(const float* __restrict__ ctx, const float* __restrict__ Wp,
        const float* __restrict__ bp, const float* __restrict__ bh,
        const float* __restrict__ bc, const float* __restrict__ bi,
        float* __restrict__ pT)
{
  __shared__ float lds[Bz*LDA];
  int tid=threadIdx.x; int b=tid&63;
  int wv=__builtin_amdgcn_readfirstlane(tid>>6);
  int jc0 = blockIdx.x*16 + wv*4;
  float acc[4];
  gemm_core<4, Hz>(ctx, Hz, Wp, jc0, b, tid, acc, lds);
#pragma unroll
  for(int c=0;c<4;c++){
    int j=jc0+c;
    float v = acc[c] + bp[j] + bi[j] + (j < 2*Hz ? bh[j] : bc[j-2*Hz]);
    pT[(size_t)j*64 + b] = v;
  }
}

// ---- kI: hF quad-layout init + hB bf16 init. 64 blocks x 256 thr.
// hF quad layout: hF[((j>>2)*64 + b)*4 + (j&3)]
__global__ __launch_bounds__(256)
void kI(const float* __restrict__ h0, float* __restrict__ hF, unsigned short* __restrict__ hB)
{
  int b = blockIdx.x;
  int j = threadIdx.x*4;
  float4 v = *(const float4*)(h0 + (size_t)b*Hz + j);
  *(float4*)(hF + ((size_t)(j>>2)*64 + b)*4) = v;
  unsigned long long pk = (unsigned long long)pk2(v.x,v.y)
                        | ((unsigned long long)pk2(v.z,v.w) << 32);
  *(unsigned long long*)(hB + (size_t)b*Hz + j) = pk;
}

// ---- kAm: MFMA input GEMM. igT[t][j][b] = bf16( x[b,t]·Wi[j] + pT[j][b] )
__global__ __launch_bounds__(1024)
void kAm(const float* __restrict__ x, const float* __restrict__ Wi,
         const float* __restrict__ pT, unsigned short* __restrict__ igT)
{
  __shared__ unsigned short wiF[4*16*64*8];  // 64 KB
  __shared__ unsigned short xs[64*528];      // 66 KB
  __shared__ unsigned short igs[64*64];      // 8 KB
  const int tid = threadIdx.x;
  const int lane = tid & 63;
  const int w = __builtin_amdgcn_readfirstlane(tid >> 6);
  const int j0 = blockIdx.x * 64;
  const int t0 = blockIdx.y * 16;
  const int mt = w >> 2, nt = w & 3;
  const int bb = nt*16 + (lane & 15);
  const int q  = lane >> 4;
  const int jl = mt*16 + q*4;

  for (int idx = tid; idx < 4096; idx += 1024) {
    int mt2 = idx >> 10;
    int ks = (idx >> 6) & 15;
    int ln = idx & 63;
    int j = j0 + mt2*16 + (ln & 15);
    int k = ks*32 + (ln >> 4)*8;
    const float* s = Wi + (size_t)j*Dz + k;
    unsigned short* d = wiF + (size_t)idx*8;
#pragma unroll
    for (int qq=0;qq<8;qq++) d[qq] = f2b(s[qq]);
  }
  float pv[4];
#pragma unroll
  for (int r=0;r<4;r++) pv[r] = pT[(size_t)(j0+jl+r)*64 + bb];

  for (int it=0; it<16; it++) {
    int t = t0 + it;
    __syncthreads();
    for (int i = tid; i < 64*32; i += 1024) {
      int b = i >> 5, c = i & 31;
      const float* s = x + ((size_t)b*Tz + t)*Dz + c*16;
      unsigned* d = (unsigned*)(xs + (size_t)b*528 + c*16);
      float4 v0 = *(const float4*)(s);
      float4 v1 = *(const float4*)(s+4);
      float4 v2 = *(const float4*)(s+8);
      float4 v3 = *(const float4*)(s+12);
      d[0]=pk2(v0.x,v0.y); d[1]=pk2(v0.z,v0.w);
      d[2]=pk2(v1.x,v1.y); d[3]=pk2(v1.z,v1.w);
      d[4]=pk2(v2.x,v2.y); d[5]=pk2(v2.z,v2.w);
      d[6]=pk2(v3.x,v3.y); d[7]=pk2(v3.z,v3.w);
    }
    __syncthreads();
    f32x4 acc = {0.f,0.f,0.f,0.f};
    const unsigned short* bsrc = xs + (size_t)bb*528 + q*8;
#pragma unroll
    for (int ks=0; ks<16; ks++) {
      bf16x8 a = *(const bf16x8*)(wiF + ((size_t)(mt*16+ks)*64 + lane)*8);
      bf16x8 b = *(const bf16x8*)(bsrc + ks*32);
      acc = __builtin_amdgcn_mfma_f32_16x16x32_bf16(a, b, acc, 0, 0, 0);
    }
#pragma unroll
    for (int r=0;r<4;r++) igs[(size_t)(jl+r)*64 + bb] = f2b(acc[r] + pv[r]);
    __syncthreads();
    if (tid < 512) {
      int j = tid >> 3, seg = tid & 7;
      *(uint4*)(igT + ((size_t)t*G3 + j0 + j)*64 + seg*8) =
        *(const uint4*)(igs + (size_t)j*64 + seg*8);
    }
  }
}

// ---- krec: persistent MFMA recurrence, 64 blocks x 1024 threads, fence-free.
// hF/iT: f32 quad layout [((j>>2)*64+b)*4 + (j&3)]; hB/rhB: bf16 [b][k].
// All cross-block state via relaxed agent atomics (sc1).
__global__ __launch_bounds__(1024)
void krec(const float* __restrict__ Wh, const float* __restrict__ Wc,
          const unsigned short* __restrict__ igT,
          float* __restrict__ hF, unsigned short* __restrict__ hB,
          unsigned short* __restrict__ rhB, float* __restrict__ iT,
          float* __restrict__ out, int* flags, int* gen)
{
  __shared__ unsigned short whF[2*32*64*8];  // 64 KB
  __shared__ unsigned short wcF[32*64*8];    // 32 KB
  __shared__ float red[16*64*4];             // 16 KB
  const int tid = threadIdx.x;
  const int lane = tid & 63;
  const int w = __builtin_amdgcn_readfirstlane(tid >> 6);
  const int n = blockIdx.x;

  // fragment-swizzle weight slices (f32 -> bf16), one-time
  for (int idx = tid; idx < 4096; idx += 1024) {
    int mt = idx >> 11;
    int ks = (idx >> 6) & 31;
    int ln = idx & 63;
    int j = n*32 + mt*16 + (ln & 15);
    int k = ks*32 + (ln >> 4)*8;
    const float* s = Wh + (size_t)j*Hz + k;
    unsigned short* d = whF + (size_t)idx*8;
#pragma unroll
    for (int qq=0;qq<8;qq++) d[qq] = f2b(s[qq]);
  }
  for (int idx = tid; idx < 2048; idx += 1024) {
    int ks = (idx >> 6) & 31;
    int ln = idx & 63;
    int j = n*16 + (ln & 15);
    int k = ks*32 + (ln >> 4)*8;
    const float* s = Wc + (size_t)j*Hz + k;
    unsigned short* d = wcF + (size_t)idx*8;
#pragma unroll
    for (int qq=0;qq<8;qq++) d[qq] = f2b(s[qq]);
  }

  for (int t=0;t<Tz;t++) {
    const unsigned short* igt = igT + (size_t)t*G3*64;
    // ---------- phase 1: gates r,i ----------
    {
      int tp = w & 7, kh = w >> 3;        // 8 tiles x split-K-2
      int mt = tp >> 2, nt = tp & 3;
      int bb = nt*16 + (lane & 15);
      int q  = lane >> 4;
      int jg = n*32 + mt*16 + q*4;        // gate col in [0,2048)
      float igv[4], hv[4];
      if (w < 8) {
#pragma unroll
        for (int r=0;r<4;r++) igv[r] = b2f(igt[(size_t)(jg+r)*64 + bb]);
        if (n < 32) {
          const float* hp = hF + ((size_t)(jg>>2)*64 + bb)*4;
          float2 a01 = cldf2(hp), a23 = cldf2(hp+2);
          hv[0]=a01.x; hv[1]=a01.y; hv[2]=a23.x; hv[3]=a23.y;
        }
      }
      f32x4 acc = {0.f,0.f,0.f,0.f};
      const unsigned short* bsrc = hB + (size_t)bb*Hz + q*8;
      const unsigned short* asrc = whF + ((size_t)(mt*32 + kh*16)*64 + lane)*8;
#pragma unroll
      for (int ks=0; ks<16; ks++) {
        bf16x8 a = *(const bf16x8*)(asrc + (size_t)ks*64*8);
        bf16x8 b = cldb8(bsrc + (size_t)(kh*16+ks)*32);
        acc = __builtin_amdgcn_mfma_f32_16x16x32_bf16(a, b, acc, 0, 0, 0);
      }
      *(f32x4*)(red + ((size_t)w*64 + lane)*4) = acc;
      __syncthreads();
      if (w < 8) {
        f32x4 o  = *(const f32x4*)(red + ((size_t)w*64+lane)*4);
        f32x4 p2 = *(const f32x4*)(red + ((size_t)(w+8)*64+lane)*4);
        if (n < 32) {
          unsigned long long pk = 0;
#pragma unroll
          for (int r=0;r<4;r++) {
            float g = sigm(o[r] + p2[r] + igv[r]);
            pk |= (unsigned long long)f2b(g * hv[r]) << (16*r);
          }
          cst64(rhB + (size_t)bb*Hz + jg, pk);
        } else {
          float g0 = sigm(o[0] + p2[0] + igv[0]);
          float g1 = sigm(o[1] + p2[1] + igv[1]);
          float g2 = sigm(o[2] + p2[2] + igv[2]);
          float g3 = sigm(o[3] + p2[3] + igv[3]);
          float* ip = iT + ((size_t)((jg-1024)>>2)*64 + bb)*4;
          cstf2(ip, g0, g1); cstf2(ip+2, g2, g3);
        }
      }
    }
    gbar(flags, gen, 2*t+1);
    // ---------- phase 2: n-gate + h update ----------
    {
      int nt = w & 3, kq = w >> 2;        // 4 tiles x split-K-4
      int bb = nt*16 + (lane & 15);
      int q  = lane >> 4;
      int jn = n*16 + q*4;                // col in [0,1024)
      float igv[4], hv[4], iv[4];
      if (w < 4) {
#pragma unroll
        for (int r=0;r<4;r++) igv[r] = b2f(igt[(size_t)(2048+jn+r)*64 + bb]);
        const float* hp = hF + ((size_t)(jn>>2)*64 + bb)*4;
        float2 a01 = cldf2(hp), a23 = cldf2(hp+2);
        hv[0]=a01.x; hv[1]=a01.y; hv[2]=a23.x; hv[3]=a23.y;
        const float* ip = iT + ((size_t)(jn>>2)*64 + bb)*4;
        float2 b01 = cldf2(ip), b23 = cldf2(ip+2);
        iv[0]=b01.x; iv[1]=b01.y; iv[2]=b23.x; iv[3]=b23.y;
      }
      f32x4 acc = {0.f,0.f,0.f,0.f};
      const unsigned short* bsrc = rhB + (size_t)bb*Hz + q*8;
#pragma unroll
      for (int ks=0; ks<8; ks++) {
        bf16x8 a = *(const bf16x8*)(wcF + ((size_t)(kq*8+ks)*64 + lane)*8);
        bf16x8 b = cldb8(bsrc + (size_t)(kq*8+ks)*32);
        acc = __builtin_amdgcn_mfma_f32_16x16x32_bf16(a, b, acc, 0, 0, 0);
      }
      *(f32x4*)(red + ((size_t)w*64 + lane)*4) = acc;
      __syncthreads();
      if (w < 4) {
        f32x4 s0 = *(const f32x4*)(red + ((size_t)w*64+lane)*4);
        f32x4 s1 = *(const f32x4*)(red + ((size_t)(w+4)*64+lane)*4);
        f32x4 s2 = *(const f32x4*)(red + ((size_t)(w+8)*64+lane)*4);
        f32x4 s3 = *(const f32x4*)(red + ((size_t)(w+12)*64+lane)*4);
        float hy4[4];
        unsigned long long pk = 0;
#pragma unroll
        for (int r=0;r<4;r++) {
          float g  = s0[r]+s1[r]+s2[r]+s3[r] + igv[r];
          float ng = tanhf(g);
          float hy = hv[r] + iv[r]*(ng - hv[r]);
          hy4[r] = hy;
          pk |= (unsigned long long)f2b(hy) << (16*r);
        }
        float* hp = hF + ((size_t)(jn>>2)*64 + bb)*4;
        cstf2(hp,   hy4[0], hy4[1]);
        cstf2(hp+2, hy4[2], hy4[3]);
        cst64(hB + (size_t)bb*Hz + jn, pk);
        float4 ov; ov.x=hy4[0]; ov.y=hy4[1]; ov.z=hy4[2]; ov.w=hy4[3];
        *(float4*)(out + ((size_t)bb*Tz + t)*Hz + jn) = ov;
      }
    }
    gbar(flags, gen, 2*t+2);
  }
}

// ---- final hidden state: hN[b][j] = hF(quad)[j][b]
__global__ __launch_bounds__(256)
void ktr(const float* __restrict__ hF, float* __restrict__ hN)
{
  int b = blockIdx.x;
  int j = threadIdx.x*4;
  float4 v = *(const float4*)(hF + ((size_t)(j>>2)*64 + b)*4);
  *(float4*)(hN + (size_t)b*Hz + j) = v;
}

extern "C" void kernel_launch(void* const* d_in, const int* in_sizes, int n_in,
                              void* d_out, int out_size, void* d_ws, size_t ws_size,
                              hipStream_t stream)
{
  const float* x   = (const float*)d_in[0];
  const float* h0  = (const float*)d_in[1];
  const float* ctx = (const float*)d_in[2];
  const float* Wi  = (const float*)d_in[3];
  const float* bi  = (const float*)d_in[4];
  const float* Wh  = (const float*)d_in[5];
  const float* bh  = (const float*)d_in[6];
  const float* Wp  = (const float*)d_in[7];
  const float* bp  = (const float*)d_in[8];
  const float* Wc  = (const float*)d_in[9];
  const float* bc  = (const float*)d_in[10];
  float* out = (float*)d_out;

  char* wsp = (char*)d_ws;
  float* pT  = (float*)wsp; wsp += (size_t)G3*64*sizeof(float);       // 768 KB
  float* hF  = (float*)wsp; wsp += (size_t)Hz*64*sizeof(float);       // 256 KB
  float* iT  = (float*)wsp; wsp += (size_t)Hz*64*sizeof(float);       // 256 KB
  unsigned short* hB  = (unsigned short*)wsp; wsp += (size_t)Bz*Hz*2; // 128 KB
  unsigned short* rhB = (unsigned short*)wsp; wsp += (size_t)Bz*Hz*2; // 128 KB
  int* flags = (int*)wsp; wsp += 512;                                 // flags[64] + gen
  int* gen = flags + 96;
  unsigned short* igT = (unsigned short*)wsp;                         // 96 MB

  hipMemsetAsync(flags, 0, 512, stream);
  kP  <<<dim3(G3/16),   256,  0, stream>>>(ctx, Wp, bp, bh, bc, bi, pT);
  kI  <<<dim3(64),      256,  0, stream>>>(h0, hF, hB);
  kAm <<<dim3(48,16),   1024, 0, stream>>>(x, Wi, pT, igT);
  krec<<<dim3(NBK),     1024, 0, stream>>>(Wh, Wc, igT, hF, hB, rhB, iT, out, flags, gen);
  ktr <<<dim3(64),      256,  0, stream>>>(hF, out + (size_t)Bz*Tz*Hz);
}